// Round 1
// baseline (376.677 us; speedup 1.0000x reference)
//
#include <hip/hip_runtime.h>
#include <cstdint>
#include <cstddef>

typedef __bf16 bf16x8 __attribute__((ext_vector_type(8)));
typedef float f32x4 __attribute__((ext_vector_type(4)));
typedef unsigned short u16;
typedef unsigned short u16x8 __attribute__((ext_vector_type(8)));

#define BATCH 4096
#define NE 8

__device__ __forceinline__ u16 f2bf(float f) {
  union { float f; uint32_t u; } v; v.f = f;
  uint32_t u = v.u;
  u += 0x7fffu + ((u >> 16) & 1u);   // RTNE
  return (u16)(u >> 16);
}

__device__ __forceinline__ float bf2f(u16 u) {
  union { uint32_t u; float f; } v; v.u = ((uint32_t)u) << 16;
  return v.f;
}

__device__ __forceinline__ void cast8(const float* src, u16* dst) {
  const float4* p = (const float4*)src;
  float4 a = p[0], b = p[1];
  u16x8 o;
  o[0] = f2bf(a.x); o[1] = f2bf(a.y); o[2] = f2bf(a.z); o[3] = f2bf(a.w);
  o[4] = f2bf(b.x); o[5] = f2bf(b.y); o[6] = f2bf(b.z); o[7] = f2bf(b.w);
  *(u16x8*)dst = o;
}

// One dispatch: h0 = bf16(x); W0/W1/W2 (E,N,K0) fp32 -> Bt (N, E*K0) bf16.
__device__ __forceinline__ void conv_w_chunk(const float* __restrict__ W,
                                             u16* __restrict__ Bt,
                                             int N, int K0, int chunk) {
  int per_row = K0 >> 3;
  int rid = chunk / per_row;             // rid = e*N + o
  int i0 = (chunk - rid * per_row) << 3;
  int e = rid / N;
  int o = rid - e * N;
  cast8(W + (size_t)rid * K0 + i0,
        Bt + (size_t)o * ((size_t)NE * K0) + (size_t)e * K0 + i0);
}

__global__ void prep_kernel(const float* __restrict__ x,
                            const float* __restrict__ W0,
                            const float* __restrict__ W1,
                            const float* __restrict__ W2,
                            u16* __restrict__ h0, u16* __restrict__ Bt0,
                            u16* __restrict__ Bt1, u16* __restrict__ Bt2) {
  int t = blockIdx.x * blockDim.x + threadIdx.x;
  const int C0 = BATCH * 512 / 8;            // x cast:   262144
  const int C1 = C0 + NE * 1024 * 512 / 8;   // W0:      +524288
  const int C2 = C1 + NE * 1024 * 1024 / 8;  // W1:      +1048576
  if (t < C0) {
    cast8(x + (size_t)t * 8, h0 + (size_t)t * 8);
  } else if (t < C1) {
    conv_w_chunk(W0, Bt0, 1024, 512, t - C0);
  } else if (t < C2) {
    conv_w_chunk(W1, Bt1, 1024, 1024, t - C1);
  } else {
    conv_w_chunk(W2, Bt2, 512, 1024, t - C2);
  }
}

// out = [act](sum_s P_s + blend @ Bias), P_s bf16; bf16 or fp32 out.
template<int SLICES, bool ELU_ACT, bool OUT_BF16>
__global__ void combineS_kernel(const u16* __restrict__ P,
                                const float* __restrict__ blend,
                                const float* __restrict__ Bias,
                                void* __restrict__ outp, int N) {
  int t = blockIdx.x * blockDim.x + threadIdx.x;
  int per_row = N >> 3;
  int b = t / per_row;
  int i0 = (t - b * per_row) << 3;
  const size_t slice = (size_t)BATCH * N;
  float v[8] = {0, 0, 0, 0, 0, 0, 0, 0};
  #pragma unroll
  for (int s = 0; s < SLICES; ++s) {
    u16x8 pv = *(const u16x8*)(P + (size_t)s * slice + (size_t)b * N + i0);
    #pragma unroll
    for (int j = 0; j < 8; ++j) v[j] += bf2f(pv[j]);
  }
  const float4* blp = (const float4*)(blend + b * NE);
  float4 u0 = blp[0], u1 = blp[1];
  float bl[8] = {u0.x, u0.y, u0.z, u0.w, u1.x, u1.y, u1.z, u1.w};
  #pragma unroll
  for (int e = 0; e < NE; ++e) {
    const float4* bp = (const float4*)(Bias + (size_t)e * N + i0);
    float4 ba = bp[0], bb = bp[1];
    float bv[8] = {ba.x, ba.y, ba.z, ba.w, bb.x, bb.y, bb.z, bb.w};
    #pragma unroll
    for (int j = 0; j < 8; ++j) v[j] += bl[e] * bv[j];
  }
  if (ELU_ACT) {
    #pragma unroll
    for (int j = 0; j < 8; ++j) v[j] = v[j] > 0.f ? v[j] : expm1f(v[j]);
  }
  if (OUT_BF16) {
    u16x8 o;
    #pragma unroll
    for (int j = 0; j < 8; ++j) o[j] = f2bf(v[j]);
    *(u16x8*)((u16*)outp + (size_t)b * N + i0) = o;
  } else {
    float4* op = (float4*)((float*)outp + (size_t)b * N + i0);
    op[0] = (float4){v[0], v[1], v[2], v[3]};
    op[1] = (float4){v[4], v[5], v[6], v[7]};
  }
}

#define GL2LDS(g, l) __builtin_amdgcn_global_load_lds( \
    (__attribute__((address_space(1))) void*)(g),      \
    (__attribute__((address_space(3))) void*)(l), 16, 0, 0)

// Raw barrier / counted waits: raw s_barrier does NOT drain vmcnt (unlike
// __syncthreads), which is the whole point — loads stay in flight across it.
#define SBAR  asm volatile("s_barrier" ::: "memory")
#define LGKM0 asm volatile("s_waitcnt lgkmcnt(0)" ::: "memory")
#define VMW3  asm volatile("s_waitcnt vmcnt(3)" ::: "memory")
#define VMW0  asm volatile("s_waitcnt vmcnt(0)" ::: "memory")

// 8 bf16 (one dwordx4) scaled by s, repacked bf16 (RTNE via v_cvt_pk_bf16_f32).
__device__ __forceinline__ uint4 scale8(uint4 d, float s) {
  uint32_t* pi = (uint32_t*)&d;
  uint4 o;
  uint32_t* po = (uint32_t*)&o;
  #pragma unroll
  for (int i = 0; i < 4; ++i) {
    uint32_t wv = pi[i];
    float lo = __uint_as_float(wv << 16) * s;
    float hi = __uint_as_float(wv & 0xffff0000u) * s;
    uint32_t pk;
    asm("v_cvt_pk_bf16_f32 %0, %1, %2" : "=v"(pk) : "v"(lo), "v"(hi));
    po[i] = pk;
  }
  return o;
}

// Deep-pipelined blend-folded GEMM:
//   P_z[b,n] = sum_{e in slice z} blend[b,e] * sum_k h[b,k] W[e,n,k]
// computed as ONE GEMM over K = EPB*K0 with the blend scale folded into the
// A-tile during reg-staging (global->reg->scale->swizzled ds_write), so no
// second accumulator is needed. B staged via global_load_lds with
// pre-swizzled global source (linear LDS dest).
// BM=256 BN=128 BK=32, 512 thr (8 waves 4Mx2N, per-wave 64x64 = acc[4][4]).
// Triple-buffered LDS (3 x 24 KB) -> prefetch runs 2 K-tiles ahead; raw
// s_barrier + counted s_waitcnt vmcnt(3) (never 0 in steady state) keeps
// 1 gload_lds + 2 A-loads in flight across every barrier (T3/T4), setprio(1)
// around MFMA clusters (T5). A-reg dependency is compiler-tracked (exact
// counted wait emitted at the scale-use one tile later).
template<int K0, int EPB>
__global__ __launch_bounds__(512, 2)
void gemm_pipe_kernel(const u16* __restrict__ h, const u16* __restrict__ Bt,
                      const float* __restrict__ blend,
                      u16* __restrict__ P, int N) {
  constexpr int TPE  = K0 / 32;                 // K-tiles per expert
  constexpr int LTPE = (K0 == 512) ? 4 : 5;
  constexpr int NT   = EPB * TPE;               // total K-tiles (even)
  const int EK = NE * K0;

  // A bufs: 3 x 16384 B @ 0; B bufs: 3 x 8192 B @ 49152. Epilogue reuses SM.
  __shared__ __align__(16) char SM[73728];
  __shared__ float bls[256 * 9];                // blend, stride 9 (no conflicts)

  const int tid  = threadIdx.x;
  const int lane = tid & 63, w = tid >> 6;
  const int wm   = w >> 1, wn = w & 1;
  const int lrow = lane & 15, quad = lane >> 4;

  const int row0 = blockIdx.x * 256;
  const int col0 = blockIdx.y * 128;
  const int e0   = blockIdx.z * EPB;

  // stage blend[row0..row0+255, 0..7] into bls
  {
    const float4 bv = ((const float4*)(blend + (size_t)row0 * NE))[tid];
    int r = tid >> 1, c = (tid & 1) * 4;
    bls[r * 9 + c + 0] = bv.x;
    bls[r * 9 + c + 1] = bv.y;
    bls[r * 9 + c + 2] = bv.z;
    bls[r * 9 + c + 3] = bv.w;
  }

  // staging geometry: sr = row-within-tile group, sc = 16B chunk
  const int sr  = tid >> 2, sc = tid & 3;
  const int csw = sc ^ (sr & 3);                // XOR-4 chunk swizzle
  const uint32_t wA0 = (uint32_t)(sr * 64 + (csw << 4));          // A ds_write
  const uint32_t wA1 = (uint32_t)((128 + sr) * 64 + (csw << 4));  // (128+sr)&3==sr&3
  const int blo0 = sr * 9, blo1 = (128 + sr) * 9;

  const u16* gA0 = h + (size_t)(row0 + sr) * K0 + sc * 8;         // rows 0..127
  const u16* gA1 = gA0 + (size_t)128 * K0;                        // rows 128..255
  const u16* gB  = Bt + (size_t)(col0 + sr) * EK + csw * 8;       // pre-swizzled src

#define KCOL(T) (((T) & (TPE - 1)) * 32)
#define KOFF(T) ((e0 + ((T) >> LTPE)) * K0 + KCOL(T))

  // fragment read offsets (XOR-4 swizzle; (row&3) == (lrow&3) for all frags)
  const int xq = quad ^ (lrow & 3);
  uint32_t aoff[4], boff[4];
  #pragma unroll
  for (int i = 0; i < 4; ++i)
    aoff[i] = (uint32_t)((wm * 64 + i * 16 + lrow) * 64 + (xq << 4));
  #pragma unroll
  for (int j = 0; j < 4; ++j)
    boff[j] = (uint32_t)((wn * 64 + j * 16 + lrow) * 64 + (xq << 4));

  f32x4 acc[4][4];
  #pragma unroll
  for (int i = 0; i < 4; ++i)
    #pragma unroll
    for (int j = 0; j < 4; ++j) acc[i][j] = (f32x4){0.f, 0.f, 0.f, 0.f};

  __syncthreads();   // bls visible before prologue writeA

  uint32_t c0 = 0, c1 = 16384, c2 = 32768;   // A-buf byte offsets; B = 49152 + c>>1
  uint4 sE0, sE1, sO0, sO1;                  // A staging regs (2 tiles in flight)

  // ---- prologue: stage tiles 0 and 1, write A(0), drain once ----
  GL2LDS(gB + KOFF(0), SM + 49152 + (c0 >> 1) + (size_t)tid * 16);
  sE0 = *(const uint4*)(gA0 + KCOL(0));
  sE1 = *(const uint4*)(gA1 + KCOL(0));
  GL2LDS(gB + KOFF(1), SM + 49152 + (c1 >> 1) + (size_t)tid * 16);
  sO0 = *(const uint4*)(gA0 + KCOL(1));
  sO1 = *(const uint4*)(gA1 + KCOL(1));
  {
    const float bl0 = bls[blo0 + e0], bl1 = bls[blo1 + e0];
    *(uint4*)(SM + c0 + wA0) = scale8(sE0, bl0);
    *(uint4*)(SM + c0 + wA1) = scale8(sE1, bl1);
  }
  VMW0; LGKM0; SBAR;

// One K-tile: P1 {frag reads, prefetch L(T+2), 8 MFMA, writeA(T+1)} | barrier |
// P2 {frag reads, 8 MFMA} | counted vmcnt | lgkm drain | barrier.
#define TILE(T, CUR, NXT, NN, LD0, LD1, WR0, WR1)                               \
  {                                                                             \
    bf16x8 bfr[4], afr[2];                                                      \
    _Pragma("unroll")                                                           \
    for (int j = 0; j < 4; ++j)                                                 \
      bfr[j] = *(const bf16x8*)(SM + 49152 + ((CUR) >> 1) + boff[j]);           \
    _Pragma("unroll")                                                           \
    for (int i = 0; i < 2; ++i)                                                 \
      afr[i] = *(const bf16x8*)(SM + (CUR) + aoff[i]);                          \
    if ((T) + 2 < NT) {                                                         \
      GL2LDS(gB + KOFF((T) + 2), SM + 49152 + ((NN) >> 1) + (size_t)tid * 16);  \
      LD0 = *(const uint4*)(gA0 + KCOL((T) + 2));                               \
      LD1 = *(const uint4*)(gA1 + KCOL((T) + 2));                               \
    }                                                                           \
    __builtin_amdgcn_s_setprio(1);                                              \
    _Pragma("unroll")                                                           \
    for (int i = 0; i < 2; ++i)                                                 \
      _Pragma("unroll")                                                         \
      for (int j = 0; j < 4; ++j)                                               \
        acc[i][j] = __builtin_amdgcn_mfma_f32_16x16x32_bf16(afr[i], bfr[j],     \
                                                            acc[i][j], 0, 0, 0);\
    __builtin_amdgcn_s_setprio(0);                                              \
    if ((T) + 1 < NT) {                                                         \
      const int e_ = e0 + (((T) + 1) >> LTPE);                                  \
      const float bl0_ = bls[blo0 + e_], bl1_ = bls[blo1 + e_];                 \
      *(uint4*)(SM + (NXT) + wA0) = scale8(WR0, bl0_);                          \
      *(uint4*)(SM + (NXT) + wA1) = scale8(WR1, bl1_);                          \
    }                                                                           \
    SBAR;                                                                       \
    _Pragma("unroll")                                                           \
    for (int i = 0; i < 2; ++i)                                                 \
      afr[i] = *(const bf16x8*)(SM + (CUR) + aoff[2 + i]);                      \
    __builtin_amdgcn_s_setprio(1);                                              \
    _Pragma("unroll")                                                           \
    for (int i = 0; i < 2; ++i)                                                 \
      _Pragma("unroll")                                                         \
      for (int j = 0; j < 4; ++j)                                               \
        acc[2 + i][j] = __builtin_amdgcn_mfma_f32_16x16x32_bf16(                \
            afr[i], bfr[j], acc[2 + i][j], 0, 0, 0);                            \
    __builtin_amdgcn_s_setprio(0);                                              \
    if ((T) + 2 < NT) { VMW3; } else { VMW0; }                                  \
    LGKM0;                                                                      \
    SBAR;                                                                       \
  }

  #pragma unroll 1
  for (int t = 0; t < NT; t += 2) {
    TILE(t,     c0, c1, c2, sE0, sE1, sO0, sO1);
    TILE(t + 1, c1, c2, c0, sO0, sO1, sE0, sE1);
    const uint32_t tmp = c2; c2 = c1; c1 = c0; c0 = tmp;
  }
#undef TILE
#undef KOFF
#undef KCOL

  // Coalesced epilogue via per-wave LDS transpose (SM free after final barrier;
  // each wave uses a private 4 KB segment). C/D: col=lane&15, row=quad*4+reg.
  u16* Ps = P + (size_t)blockIdx.z * ((size_t)BATCH * N);
  u16* ls = (u16*)SM + w * 2048;   // 32 rows x 64 cols u16 per wave
  #pragma unroll
  for (int half = 0; half < 2; ++half) {
    #pragma unroll
    for (int mh = 0; mh < 2; ++mh) {
      int mt = half * 2 + mh;
      #pragma unroll
      for (int r = 0; r < 4; ++r) {
        int rloc = mh * 16 + quad * 4 + r;          // 0..31
        #pragma unroll
        for (int nt = 0; nt < 4; ++nt) {
          int col = nt * 16 + lrow;                 // 0..63
          int c8 = (col >> 3) ^ (rloc & 7);         // XOR-8 chunk swizzle
          ls[rloc * 64 + (c8 << 3) + (col & 7)] = f2bf(acc[mt][nt][r]);
        }
      }
    }
    #pragma unroll
    for (int p = 0; p < 4; ++p) {
      int rloc = p * 8 + (lane >> 3);               // 0..31
      int c8 = (lane & 7) ^ (rloc & 7);
      u16x8 v = *(const u16x8*)&ls[rloc * 64 + (c8 << 3)];
      int row = row0 + wm * 64 + half * 32 + rloc;
      int colg = col0 + wn * 64 + ((lane & 7) << 3);
      *(u16x8*)&Ps[(size_t)row * N + colg] = v;
    }
  }
}

extern "C" void kernel_launch(void* const* d_in, const int* in_sizes, int n_in,
                              void* d_out, int out_size, void* d_ws, size_t ws_size,
                              hipStream_t stream) {
  const float* blend = (const float*)d_in[0];
  const float* x  = (const float*)d_in[1];
  const float* W0 = (const float*)d_in[2];
  const float* B0 = (const float*)d_in[3];
  const float* W1 = (const float*)d_in[4];
  const float* B1 = (const float*)d_in[5];
  const float* W2 = (const float*)d_in[6];
  const float* B2 = (const float*)d_in[7];
  float* out = (float*)d_out;

  char* ws = (char*)d_ws;
  u16* hA  = (u16*)ws;                           // h0 (4096x512) then h2 (4096x1024); 8.4 MB
  u16* h1  = (u16*)(ws + 8388608);               // 4096x1024 bf16, 8.4 MB
  u16* Bt0 = (u16*)(ws + 16777216);              // 1024 x 4096 bf16, 8.4 MB
  u16* Bt1 = (u16*)(ws + 25165824);              // 1024 x 8192 bf16, 16.8 MB
  u16* Bt2 = (u16*)(ws + 41943040);              // 512 x 8192 bf16, 8.4 MB
  u16* P   = (u16*)(ws + 50331648);              // bf16 partials, <= 16.8 MB (unchanged)

  // prep: cast x -> h0 and convert all three W to bf16 Bt layout (one dispatch)
  prep_kernel<<<9216, 256, 0, stream>>>(x, W0, W1, W2, hA, Bt0, Bt1, Bt2);

  // Layer 0: K0=512, 2 slices x 4 experts (K=2048/block); bias+ELU in combine
  gemm_pipe_kernel<512, 4><<<dim3(16, 8, 2), 512, 0, stream>>>(hA, Bt0, blend, P, 1024);
  combineS_kernel<2, true, true><<<2048, 256, 0, stream>>>(P, blend, B0, h1, 1024);

  // Layer 1: K0=1024, 2 slices x 4 experts (K=4096/block)
  gemm_pipe_kernel<1024, 4><<<dim3(16, 8, 2), 512, 0, stream>>>(h1, Bt1, blend, P, 1024);
  combineS_kernel<2, true, true><<<2048, 256, 0, stream>>>(P, blend, B1, hA, 1024);

  // Layer 2: K0=1024, N=512, 4 slices x 2 experts (K=2048/block); linear, fp32 out
  gemm_pipe_kernel<1024, 2><<<dim3(16, 4, 4), 512, 0, stream>>>(hA, Bt2, blend, P, 512);
  combineS_kernel<4, false, false><<<1024, 256, 0, stream>>>(P, blend, B2, out, 512);
}

// Round 2
// 326.217 us; speedup vs baseline: 1.1547x; 1.1547x over previous
//
#include <hip/hip_runtime.h>
#include <cstdint>
#include <cstddef>

typedef __bf16 bf16x8 __attribute__((ext_vector_type(8)));
typedef float f32x4 __attribute__((ext_vector_type(4)));
typedef unsigned short u16;
typedef unsigned short u16x8 __attribute__((ext_vector_type(8)));

#define BATCH 4096
#define NE 8

__device__ __forceinline__ u16 f2bf(float f) {
  union { float f; uint32_t u; } v; v.f = f;
  uint32_t u = v.u;
  u += 0x7fffu + ((u >> 16) & 1u);   // RTNE
  return (u16)(u >> 16);
}

__device__ __forceinline__ float bf2f(u16 u) {
  union { uint32_t u; float f; } v; v.u = ((uint32_t)u) << 16;
  return v.f;
}

__device__ __forceinline__ void cast8(const float* src, u16* dst) {
  const float4* p = (const float4*)src;
  float4 a = p[0], b = p[1];
  u16x8 o;
  o[0] = f2bf(a.x); o[1] = f2bf(a.y); o[2] = f2bf(a.z); o[3] = f2bf(a.w);
  o[4] = f2bf(b.x); o[5] = f2bf(b.y); o[6] = f2bf(b.z); o[7] = f2bf(b.w);
  *(u16x8*)dst = o;
}

// One dispatch: h0 = bf16(x); W0/W1/W2 (E,N,K0) fp32 -> Bt (N, E*K0) bf16.
__device__ __forceinline__ void conv_w_chunk(const float* __restrict__ W,
                                             u16* __restrict__ Bt,
                                             int N, int K0, int chunk) {
  int per_row = K0 >> 3;
  int rid = chunk / per_row;             // rid = e*N + o
  int i0 = (chunk - rid * per_row) << 3;
  int e = rid / N;
  int o = rid - e * N;
  cast8(W + (size_t)rid * K0 + i0,
        Bt + (size_t)o * ((size_t)NE * K0) + (size_t)e * K0 + i0);
}

__global__ void prep_kernel(const float* __restrict__ x,
                            const float* __restrict__ W0,
                            const float* __restrict__ W1,
                            const float* __restrict__ W2,
                            u16* __restrict__ h0, u16* __restrict__ Bt0,
                            u16* __restrict__ Bt1, u16* __restrict__ Bt2) {
  int t = blockIdx.x * blockDim.x + threadIdx.x;
  const int C0 = BATCH * 512 / 8;            // x cast:   262144
  const int C1 = C0 + NE * 1024 * 512 / 8;   // W0:      +524288
  const int C2 = C1 + NE * 1024 * 1024 / 8;  // W1:      +1048576
  if (t < C0) {
    cast8(x + (size_t)t * 8, h0 + (size_t)t * 8);
  } else if (t < C1) {
    conv_w_chunk(W0, Bt0, 1024, 512, t - C0);
  } else if (t < C2) {
    conv_w_chunk(W1, Bt1, 1024, 1024, t - C1);
  } else {
    conv_w_chunk(W2, Bt2, 512, 1024, t - C2);
  }
}

// out = [act](sum_s P_s + blend @ Bias), P_s bf16; bf16 or fp32 out.
template<int SLICES, bool ELU_ACT, bool OUT_BF16>
__global__ void combineS_kernel(const u16* __restrict__ P,
                                const float* __restrict__ blend,
                                const float* __restrict__ Bias,
                                void* __restrict__ outp, int N) {
  int t = blockIdx.x * blockDim.x + threadIdx.x;
  int per_row = N >> 3;
  int b = t / per_row;
  int i0 = (t - b * per_row) << 3;
  const size_t slice = (size_t)BATCH * N;
  float v[8] = {0, 0, 0, 0, 0, 0, 0, 0};
  #pragma unroll
  for (int s = 0; s < SLICES; ++s) {
    u16x8 pv = *(const u16x8*)(P + (size_t)s * slice + (size_t)b * N + i0);
    #pragma unroll
    for (int j = 0; j < 8; ++j) v[j] += bf2f(pv[j]);
  }
  const float4* blp = (const float4*)(blend + b * NE);
  float4 u0 = blp[0], u1 = blp[1];
  float bl[8] = {u0.x, u0.y, u0.z, u0.w, u1.x, u1.y, u1.z, u1.w};
  #pragma unroll
  for (int e = 0; e < NE; ++e) {
    const float4* bp = (const float4*)(Bias + (size_t)e * N + i0);
    float4 ba = bp[0], bb = bp[1];
    float bv[8] = {ba.x, ba.y, ba.z, ba.w, bb.x, bb.y, bb.z, bb.w};
    #pragma unroll
    for (int j = 0; j < 8; ++j) v[j] += bl[e] * bv[j];
  }
  if (ELU_ACT) {
    #pragma unroll
    for (int j = 0; j < 8; ++j) v[j] = v[j] > 0.f ? v[j] : expm1f(v[j]);
  }
  if (OUT_BF16) {
    u16x8 o;
    #pragma unroll
    for (int j = 0; j < 8; ++j) o[j] = f2bf(v[j]);
    *(u16x8*)((u16*)outp + (size_t)b * N + i0) = o;
  } else {
    float4* op = (float4*)((float*)outp + (size_t)b * N + i0);
    op[0] = (float4){v[0], v[1], v[2], v[3]};
    op[1] = (float4){v[4], v[5], v[6], v[7]};
  }
}

#define GL2LDS(g, l) __builtin_amdgcn_global_load_lds( \
    (__attribute__((address_space(1))) void*)(g),      \
    (__attribute__((address_space(3))) void*)(l), 16, 0, 0)

// Raw barrier (does NOT drain counters, unlike __syncthreads) + explicit waits.
#define SBAR  asm volatile("s_barrier" ::: "memory")
#define LGKM0 asm volatile("s_waitcnt lgkmcnt(0)" ::: "memory")
#define VMW0  asm volatile("s_waitcnt vmcnt(0)" ::: "memory")

// 8 bf16 (one dwordx4) scaled by s, repacked bf16 (RTNE via v_cvt_pk_bf16_f32).
__device__ __forceinline__ uint4 scale8(uint4 d, float s) {
  uint32_t* pi = (uint32_t*)&d;
  uint4 o;
  uint32_t* po = (uint32_t*)&o;
  #pragma unroll
  for (int i = 0; i < 4; ++i) {
    uint32_t wv = pi[i];
    float lo = __uint_as_float(wv << 16) * s;
    float hi = __uint_as_float(wv & 0xffff0000u) * s;
    uint32_t pk;
    asm("v_cvt_pk_bf16_f32 %0, %1, %2" : "=v"(pk) : "v"(lo), "v"(hi));
    po[i] = pk;
  }
  return o;
}

// Blend-folded deep-pipelined GEMM on the r6-proven geometry:
//   P_z[b,n] = sum_{e in slice z} blend[b,e] * sum_k h[b,k] W[e,n,k]
// = ONE GEMM over K = EPB*K0 with blend folded into the A-tile during
// reg-staging (global->reg->scale->XOR-8-swizzled ds_write). B staged via
// global_load_lds with pre-swizzled source (linear LDS dest).
// BM=BN=128, BK=64, 256 thr / 4 waves (2x2), per-wave 64x64 = acc[4][4].
// LDS rows are 128 B (8 x 16 B chunks), XOR-8 chunk swizzle on write AND
// read (same involution) -> conflict-free ds_read_b128 (r6-verified).
// Double-buffered (A 16K x2 + B 16K x2 = 64 KB + bls) -> 2 blocks/CU.
// Per 64-K tile: issue A-reg loads(t+1) + 4 GL2LDS B(t+1) -> frag+MFMA kc0
// -> scale+ds_write A(t+1) (compiler-counted vmcnt(4): GL2LDS stay in
// flight) -> frag+MFMA kc1 -> vmcnt(0) (GL2LDS issued a full tile ago,
// latency hidden) -> lgkmcnt(0) -> ONE raw s_barrier. setprio(1) on MFMA.
template<int K0, int EPB>
__global__ __launch_bounds__(256, 2)
void gemm_pipe_kernel(const u16* __restrict__ h, const u16* __restrict__ Bt,
                      const float* __restrict__ blend,
                      u16* __restrict__ P, int N) {
  constexpr int TPE  = K0 / 64;                 // K-tiles per expert
  constexpr int LTPE = (K0 == 512) ? 3 : 4;
  constexpr int NT   = EPB * TPE;               // total K-tiles (even)
  constexpr int EK   = NE * K0;

  // A0@0, A1@16384, B0@32768, B1@49152 (each 16 KB). Epilogue reuses SM.
  __shared__ __align__(16) char SM[65536];
  __shared__ float bls[128 * 9];                // blend, stride 9 (no conflicts)

  const int tid  = threadIdx.x;
  const int lane = tid & 63, w = tid >> 6;
  const int wm   = w >> 1, wn = w & 1;
  const int lrow = lane & 15, quad = lane >> 4;

  const int row0 = blockIdx.x * 128;
  const int col0 = blockIdx.y * 128;
  const int e0   = blockIdx.z * EPB;

  // stage blend[row0..row0+127, 0..7] into bls
  {
    const float4 bv = ((const float4*)(blend + (size_t)row0 * NE))[tid];
    int r = tid >> 1, c = (tid & 1) * 4;
    bls[r * 9 + c + 0] = bv.x;
    bls[r * 9 + c + 1] = bv.y;
    bls[r * 9 + c + 2] = bv.z;
    bls[r * 9 + c + 3] = bv.w;
  }

  // staging geometry: sr = row (0..31 per pass), sc = 16B chunk (0..7)
  const int sr  = tid >> 3, sc = tid & 7;
  const int tcol = sc ^ (sr & 7);               // XOR-8 chunk swizzle
  const uint32_t swA0 = (uint32_t)(sr * 128 + (tcol << 4));   // A ds_write base
  const int blo0 = sr * 9;

  const u16* gA = h + (size_t)(row0 + sr) * K0 + sc * 8;      // linear A source
  const u16* gB = Bt + (size_t)(col0 + sr) * EK + tcol * 8;   // pre-swz B source

#define KCOL(T)  (((T) & (TPE - 1)) * 64)
#define KOFFB(T) ((e0 + ((T) >> LTPE)) * K0 + KCOL(T))

  // fragment read byte offsets (XOR-8; row&7 == lrow&7 for all frag rows)
  const int xr = lrow & 7;
  uint32_t aoff[2][4], boff[2][4];
  #pragma unroll
  for (int kc = 0; kc < 2; ++kc)
    #pragma unroll
    for (int i = 0; i < 4; ++i) {
      aoff[kc][i] = (uint32_t)((wm * 64 + i * 16 + lrow) * 128 +
                               (((kc * 4 + quad) ^ xr) << 4));
      boff[kc][i] = (uint32_t)((wn * 64 + i * 16 + lrow) * 128 +
                               (((kc * 4 + quad) ^ xr) << 4));
    }

  f32x4 acc[4][4];
  #pragma unroll
  for (int i = 0; i < 4; ++i)
    #pragma unroll
    for (int j = 0; j < 4; ++j) acc[i][j] = (f32x4){0.f, 0.f, 0.f, 0.f};

  __syncthreads();   // bls visible before first scale

  // ---- prologue: stage tile 0 into A0/B0, drain once ----
  {
    const u16* pa = gA;                // KCOL(0) = 0
    uint4 a0 = *(const uint4*)(pa);
    uint4 a1 = *(const uint4*)(pa + 32 * K0);
    uint4 a2 = *(const uint4*)(pa + 64 * K0);
    uint4 a3 = *(const uint4*)(pa + 96 * K0);
    const u16* pb = gB + (size_t)e0 * K0;
    GL2LDS(pb,               SM + 32768 + (size_t)tid * 16);
    GL2LDS(pb + 32 * EK,     SM + 32768 + 4096 + (size_t)tid * 16);
    GL2LDS(pb + 64 * EK,     SM + 32768 + 8192 + (size_t)tid * 16);
    GL2LDS(pb + 96 * EK,     SM + 32768 + 12288 + (size_t)tid * 16);
    *(uint4*)(SM + swA0)          = scale8(a0, bls[blo0 + e0]);
    *(uint4*)(SM + swA0 + 4096)   = scale8(a1, bls[blo0 + 288 + e0]);
    *(uint4*)(SM + swA0 + 8192)   = scale8(a2, bls[blo0 + 576 + e0]);
    *(uint4*)(SM + swA0 + 12288)  = scale8(a3, bls[blo0 + 864 + e0]);
    VMW0; LGKM0; SBAR;
  }

// One 64-K tile: prefetch(t+1) || {frags+MFMA kc0} -> ds_write A(t+1)
// -> {frags+MFMA kc1} -> vmcnt(0) lgkmcnt(0) -> ONE s_barrier.
#define TILE(T, CA, CB, NA, NB)                                                 \
  {                                                                             \
    const int tn = (T) + 1;                                                     \
    uint4 a0, a1, a2, a3;                                                       \
    if (tn < NT) {                                                              \
      const u16* pa = gA + KCOL(tn);                                            \
      a0 = *(const uint4*)(pa);                                                 \
      a1 = *(const uint4*)(pa + 32 * K0);                                       \
      a2 = *(const uint4*)(pa + 64 * K0);                                       \
      a3 = *(const uint4*)(pa + 96 * K0);                                       \
      const u16* pb = gB + KOFFB(tn);                                           \
      GL2LDS(pb,           SM + (NB) + (size_t)tid * 16);                       \
      GL2LDS(pb + 32 * EK, SM + (NB) + 4096 + (size_t)tid * 16);                \
      GL2LDS(pb + 64 * EK, SM + (NB) + 8192 + (size_t)tid * 16);                \
      GL2LDS(pb + 96 * EK, SM + (NB) + 12288 + (size_t)tid * 16);               \
    }                                                                           \
    bf16x8 af[4], bfv[4];                                                       \
    _Pragma("unroll")                                                           \
    for (int i = 0; i < 4; ++i) af[i] = *(const bf16x8*)(SM + (CA) + aoff[0][i]); \
    _Pragma("unroll")                                                           \
    for (int j = 0; j < 4; ++j) bfv[j] = *(const bf16x8*)(SM + (CB) + boff[0][j]); \
    __builtin_amdgcn_s_setprio(1);                                              \
    _Pragma("unroll")                                                           \
    for (int i = 0; i < 4; ++i)                                                 \
      _Pragma("unroll")                                                         \
      for (int j = 0; j < 4; ++j)                                               \
        acc[i][j] = __builtin_amdgcn_mfma_f32_16x16x32_bf16(af[i], bfv[j],      \
                                                            acc[i][j], 0, 0, 0);\
    __builtin_amdgcn_s_setprio(0);                                              \
    if (tn < NT) {                                                              \
      const int e_ = e0 + (tn >> LTPE);                                         \
      *(uint4*)(SM + (NA) + swA0)         = scale8(a0, bls[blo0 + e_]);         \
      *(uint4*)(SM + (NA) + swA0 + 4096)  = scale8(a1, bls[blo0 + 288 + e_]);   \
      *(uint4*)(SM + (NA) + swA0 + 8192)  = scale8(a2, bls[blo0 + 576 + e_]);   \
      *(uint4*)(SM + (NA) + swA0 + 12288) = scale8(a3, bls[blo0 + 864 + e_]);   \
    }                                                                           \
    _Pragma("unroll")                                                           \
    for (int i = 0; i < 4; ++i) af[i] = *(const bf16x8*)(SM + (CA) + aoff[1][i]); \
    _Pragma("unroll")                                                           \
    for (int j = 0; j < 4; ++j) bfv[j] = *(const bf16x8*)(SM + (CB) + boff[1][j]); \
    __builtin_amdgcn_s_setprio(1);                                              \
    _Pragma("unroll")                                                           \
    for (int i = 0; i < 4; ++i)                                                 \
      _Pragma("unroll")                                                         \
      for (int j = 0; j < 4; ++j)                                               \
        acc[i][j] = __builtin_amdgcn_mfma_f32_16x16x32_bf16(af[i], bfv[j],      \
                                                            acc[i][j], 0, 0, 0);\
    __builtin_amdgcn_s_setprio(0);                                              \
    VMW0;                                                                       \
    LGKM0;                                                                      \
    SBAR;                                                                       \
  }

  #pragma unroll 1
  for (int t = 0; t < NT; t += 2) {
    TILE(t,     0, 32768, 16384, 49152);
    TILE(t + 1, 16384, 49152, 0, 32768);
  }
#undef TILE
#undef KOFFB
#undef KCOL

  // Coalesced epilogue via per-wave LDS transpose (SM free after final barrier;
  // each wave uses a private 4 KB segment). C/D: col=lane&15, row=quad*4+reg.
  u16* Ps = P + (size_t)blockIdx.z * ((size_t)BATCH * N);
  u16* ls = (u16*)SM + w * 2048;   // 32 rows x 64 cols u16 per wave
  #pragma unroll
  for (int half = 0; half < 2; ++half) {
    #pragma unroll
    for (int mh = 0; mh < 2; ++mh) {
      int mt = half * 2 + mh;
      #pragma unroll
      for (int r = 0; r < 4; ++r) {
        int rloc = mh * 16 + quad * 4 + r;          // 0..31
        #pragma unroll
        for (int nt = 0; nt < 4; ++nt) {
          int col = nt * 16 + lrow;                 // 0..63
          int c8 = (col >> 3) ^ (rloc & 7);         // XOR-8 chunk swizzle
          ls[rloc * 64 + (c8 << 3) + (col & 7)] = f2bf(acc[mt][nt][r]);
        }
      }
    }
    #pragma unroll
    for (int p = 0; p < 4; ++p) {
      int rloc = p * 8 + (lane >> 3);               // 0..31
      int c8 = (lane & 7) ^ (rloc & 7);
      u16x8 v = *(const u16x8*)&ls[rloc * 64 + (c8 << 3)];
      int row = row0 + wm * 64 + half * 32 + rloc;
      int colg = col0 + wn * 64 + ((lane & 7) << 3);
      *(u16x8*)&Ps[(size_t)row * N + colg] = v;
    }
  }
}

extern "C" void kernel_launch(void* const* d_in, const int* in_sizes, int n_in,
                              void* d_out, int out_size, void* d_ws, size_t ws_size,
                              hipStream_t stream) {
  const float* blend = (const float*)d_in[0];
  const float* x  = (const float*)d_in[1];
  const float* W0 = (const float*)d_in[2];
  const float* B0 = (const float*)d_in[3];
  const float* W1 = (const float*)d_in[4];
  const float* B1 = (const float*)d_in[5];
  const float* W2 = (const float*)d_in[6];
  const float* B2 = (const float*)d_in[7];
  float* out = (float*)d_out;

  char* ws = (char*)d_ws;
  u16* hA  = (u16*)ws;                           // h0 (4096x512) then h2 (4096x1024); 8.4 MB
  u16* h1  = (u16*)(ws + 8388608);               // 4096x1024 bf16, 8.4 MB
  u16* Bt0 = (u16*)(ws + 16777216);              // 1024 x 4096 bf16, 8.4 MB
  u16* Bt1 = (u16*)(ws + 25165824);              // 1024 x 8192 bf16, 16.8 MB
  u16* Bt2 = (u16*)(ws + 41943040);              // 512 x 8192 bf16, 8.4 MB
  u16* P   = (u16*)(ws + 50331648);              // bf16 partials (unchanged)

  // prep: cast x -> h0 and convert all three W to bf16 Bt layout (one dispatch)
  prep_kernel<<<9216, 256, 0, stream>>>(x, W0, W1, W2, hA, Bt0, Bt1, Bt2);

  // Layer 0: K0=512, 2 slices x 4 experts (K=2048/block); bias+ELU in combine
  gemm_pipe_kernel<512, 4><<<dim3(32, 8, 2), 256, 0, stream>>>(hA, Bt0, blend, P, 1024);
  combineS_kernel<2, true, true><<<2048, 256, 0, stream>>>(P, blend, B0, h1, 1024);

  // Layer 1: K0=1024, 2 slices x 4 experts (K=4096/block)
  gemm_pipe_kernel<1024, 4><<<dim3(32, 8, 2), 256, 0, stream>>>(h1, Bt1, blend, P, 1024);
  combineS_kernel<2, true, true><<<2048, 256, 0, stream>>>(P, blend, B1, hA, 1024);

  // Layer 2: K0=1024, N=512, 4 slices x 2 experts (K=2048/block); linear, fp32 out
  gemm_pipe_kernel<1024, 2><<<dim3(32, 4, 4), 256, 0, stream>>>(hA, Bt2, blend, P, 512);
  combineS_kernel<4, false, false><<<1024, 256, 0, stream>>>(P, blend, B2, out, 512);
}

// Round 3
// 290.140 us; speedup vs baseline: 1.2983x; 1.1243x over previous
//
#include <hip/hip_runtime.h>
#include <cstdint>
#include <cstddef>

typedef __bf16 bf16x8 __attribute__((ext_vector_type(8)));
typedef float f32x4 __attribute__((ext_vector_type(4)));
typedef unsigned short u16;
typedef unsigned short u16x8 __attribute__((ext_vector_type(8)));

#define BATCH 4096
#define NE 8

__device__ __forceinline__ u16 f2bf(float f) {
  union { float f; uint32_t u; } v; v.f = f;
  uint32_t u = v.u;
  u += 0x7fffu + ((u >> 16) & 1u);   // RTNE
  return (u16)(u >> 16);
}

__device__ __forceinline__ float bf2f(u16 u) {
  union { uint32_t u; float f; } v; v.u = ((uint32_t)u) << 16;
  return v.f;
}

__device__ __forceinline__ void cast8(const float* src, u16* dst) {
  const float4* p = (const float4*)src;
  float4 a = p[0], b = p[1];
  u16x8 o;
  o[0] = f2bf(a.x); o[1] = f2bf(a.y); o[2] = f2bf(a.z); o[3] = f2bf(a.w);
  o[4] = f2bf(b.x); o[5] = f2bf(b.y); o[6] = f2bf(b.z); o[7] = f2bf(b.w);
  *(u16x8*)dst = o;
}

// One dispatch: h0 = bf16(x); W0/W1/W2 (E,N,K0) fp32 -> Bt (N, E*K0) bf16.
__device__ __forceinline__ void conv_w_chunk(const float* __restrict__ W,
                                             u16* __restrict__ Bt,
                                             int N, int K0, int chunk) {
  int per_row = K0 >> 3;
  int rid = chunk / per_row;             // rid = e*N + o
  int i0 = (chunk - rid * per_row) << 3;
  int e = rid / N;
  int o = rid - e * N;
  cast8(W + (size_t)rid * K0 + i0,
        Bt + (size_t)o * ((size_t)NE * K0) + (size_t)e * K0 + i0);
}

__global__ void prep_kernel(const float* __restrict__ x,
                            const float* __restrict__ W0,
                            const float* __restrict__ W1,
                            const float* __restrict__ W2,
                            u16* __restrict__ h0, u16* __restrict__ Bt0,
                            u16* __restrict__ Bt1, u16* __restrict__ Bt2) {
  int t = blockIdx.x * blockDim.x + threadIdx.x;
  const int C0 = BATCH * 512 / 8;            // x cast:   262144
  const int C1 = C0 + NE * 1024 * 512 / 8;   // W0:      +524288
  const int C2 = C1 + NE * 1024 * 1024 / 8;  // W1:      +1048576
  if (t < C0) {
    cast8(x + (size_t)t * 8, h0 + (size_t)t * 8);
  } else if (t < C1) {
    conv_w_chunk(W0, Bt0, 1024, 512, t - C0);
  } else if (t < C2) {
    conv_w_chunk(W1, Bt1, 1024, 1024, t - C1);
  } else {
    conv_w_chunk(W2, Bt2, 512, 1024, t - C2);
  }
}

// out = [act](sum_s P_s + blend @ Bias), P_s bf16; bf16 or fp32 out.
template<int SLICES, bool ELU_ACT, bool OUT_BF16>
__global__ void combineS_kernel(const u16* __restrict__ P,
                                const float* __restrict__ blend,
                                const float* __restrict__ Bias,
                                void* __restrict__ outp, int N) {
  int t = blockIdx.x * blockDim.x + threadIdx.x;
  int per_row = N >> 3;
  int b = t / per_row;
  int i0 = (t - b * per_row) << 3;
  const size_t slice = (size_t)BATCH * N;
  float v[8] = {0, 0, 0, 0, 0, 0, 0, 0};
  #pragma unroll
  for (int s = 0; s < SLICES; ++s) {
    u16x8 pv = *(const u16x8*)(P + (size_t)s * slice + (size_t)b * N + i0);
    #pragma unroll
    for (int j = 0; j < 8; ++j) v[j] += bf2f(pv[j]);
  }
  const float4* blp = (const float4*)(blend + b * NE);
  float4 u0 = blp[0], u1 = blp[1];
  float bl[8] = {u0.x, u0.y, u0.z, u0.w, u1.x, u1.y, u1.z, u1.w};
  #pragma unroll
  for (int e = 0; e < NE; ++e) {
    const float4* bp = (const float4*)(Bias + (size_t)e * N + i0);
    float4 ba = bp[0], bb = bp[1];
    float bv[8] = {ba.x, ba.y, ba.z, ba.w, bb.x, bb.y, bb.z, bb.w};
    #pragma unroll
    for (int j = 0; j < 8; ++j) v[j] += bl[e] * bv[j];
  }
  if (ELU_ACT) {
    #pragma unroll
    for (int j = 0; j < 8; ++j) v[j] = v[j] > 0.f ? v[j] : expm1f(v[j]);
  }
  if (OUT_BF16) {
    u16x8 o;
    #pragma unroll
    for (int j = 0; j < 8; ++j) o[j] = f2bf(v[j]);
    *(u16x8*)((u16*)outp + (size_t)b * N + i0) = o;
  } else {
    float4* op = (float4*)((float*)outp + (size_t)b * N + i0);
    op[0] = (float4){v[0], v[1], v[2], v[3]};
    op[1] = (float4){v[4], v[5], v[6], v[7]};
  }
}

#define GL2LDS(g, l) __builtin_amdgcn_global_load_lds( \
    (__attribute__((address_space(1))) void*)(g),      \
    (__attribute__((address_space(3))) void*)(l), 16, 0, 0)

// Raw barrier (does NOT drain counters, unlike __syncthreads) + explicit waits.
#define SBAR  asm volatile("s_barrier" ::: "memory")
#define LGKM0 asm volatile("s_waitcnt lgkmcnt(0)" ::: "memory")
#define VMW6  asm volatile("s_waitcnt vmcnt(6)" ::: "memory")
#define VMW0  asm volatile("s_waitcnt vmcnt(0)" ::: "memory")

// 8-phase-style deep-pipelined expert-folding GEMM (T2+T3+T4+T5 stack on the
// r0-proven output-side fold):
//   P_z[b,n] = sum_{e in slice z} blend[b,e] * sum_k h[b,k] W[e,n,k]
// BM=256 BN=128 BK=64, 512 thr / 8 waves (4Mx2N), per-wave 64x64 = acc[4][4],
// per-expert acc2[4][4] folded as acc += blend*acc2 at expert boundaries
// (amortized over TPE tiles; zero staging VALU — all staging via
// global_load_lds with pre-swizzled global source, linear LDS dest).
// Triple-buffered LDS (3 x 48 KB: A 32K + B 16K) + blend = 153 KB ->
// 1 block/CU, grid = exactly 256 blocks (no tail). Prefetch depth 2 tiles.
// Per tile, 2 phases: {8 ds_read_b128 || 3 GL2LDS(t+2) -> s_barrier ->
// lgkmcnt(0) -> setprio(1) 16 MFMA setprio(0) -> s_barrier}; counted
// vmcnt(6) ONCE per tile (never 0 in steady state) before the tile-end
// barrier. XOR-8 chunk swizzle write-side==read-side (r0-proven, 0 conflicts).
template<int K0, int EPB>
__global__ __launch_bounds__(512, 2)
void gemm_fold8_kernel(const u16* __restrict__ h, const u16* __restrict__ Bt,
                       const float* __restrict__ blend,
                       u16* __restrict__ P, int N) {
  constexpr int TPE  = K0 / 64;                 // K-tiles per expert
  constexpr int LTPE = (K0 == 512) ? 3 : 4;     // log2(TPE)
  constexpr int NT   = EPB * TPE;               // total K-tiles (even)
  constexpr int EK   = NE * K0;

  // buffer b at b*49152: A tile 256x64 bf16 (32K) @ +0, B tile 128x64 (16K) @ +32768
  __shared__ __align__(16) char SM[147456];
  __shared__ float bls[256 * 9];                // blend, stride 9 (no conflicts)

  const int tid  = threadIdx.x;
  const int lane = tid & 63, w = tid >> 6;
  const int wm   = w >> 1, wn = w & 1;          // 4 x 2 wave grid
  const int lrow = lane & 15, quad = lane >> 4;

  const int row0 = blockIdx.x * 256;
  const int col0 = blockIdx.y * 128;
  const int e0   = blockIdx.z * EPB;

  // stage blend[row0..row0+255, 0..7] into bls (512 thr x float4 = 256 rows)
  {
    const float4 bv = ((const float4*)(blend + (size_t)row0 * NE))[tid];
    int r = tid >> 1, c = (tid & 1) * 4;
    bls[r * 9 + c + 0] = bv.x;
    bls[r * 9 + c + 1] = bv.y;
    bls[r * 9 + c + 2] = bv.z;
    bls[r * 9 + c + 3] = bv.w;
  }

  // staging geometry: sr = row 0..63 per pass, sc = 16B chunk 0..7
  const int sr  = tid >> 3, sc = tid & 7;
  const int tcol = sc ^ (sr & 7);               // XOR-8 chunk swizzle (source side)
  const u16* gA = h + (size_t)(row0 + sr) * K0 + (tcol << 3);   // rows +0/64/128/192
  const u16* gB = Bt + (size_t)(col0 + sr) * EK + (tcol << 3);  // rows +0/64

#define KCOL(T)  (((T) & (TPE - 1)) << 6)
#define KOFFB(T) ((size_t)(e0 + ((T) >> LTPE)) * K0 + KCOL(T))

  // fragment read byte offsets (XOR-8; frag-row&7 == lrow&7)
  const int xr = lrow & 7;
  uint32_t aoff[2][4], boff[2][4];
  #pragma unroll
  for (int kc = 0; kc < 2; ++kc)
    #pragma unroll
    for (int i = 0; i < 4; ++i) {
      aoff[kc][i] = (uint32_t)((wm * 64 + i * 16 + lrow) * 128 +
                               (((kc * 4 + quad) ^ xr) << 4));
      boff[kc][i] = (uint32_t)((wn * 64 + i * 16 + lrow) * 128 +
                               (((kc * 4 + quad) ^ xr) << 4));
    }

  f32x4 acc[4][4], acc2[4][4];
  #pragma unroll
  for (int i = 0; i < 4; ++i)
    #pragma unroll
    for (int j = 0; j < 4; ++j) {
      acc[i][j]  = (f32x4){0.f, 0.f, 0.f, 0.f};
      acc2[i][j] = (f32x4){0.f, 0.f, 0.f, 0.f};
    }

  // ---- prologue: stage tiles 0 (buf0) and 1 (buf1), wait tile0, barrier ----
  {
    const u16* pa = gA;                       // KCOL(0) = 0
    GL2LDS(pa,            SM + (size_t)tid * 16);
    GL2LDS(pa + 64 * K0,  SM + 8192 + (size_t)tid * 16);
    GL2LDS(pa + 128 * K0, SM + 16384 + (size_t)tid * 16);
    GL2LDS(pa + 192 * K0, SM + 24576 + (size_t)tid * 16);
    const u16* pb = gB + (size_t)e0 * K0;
    GL2LDS(pb,            SM + 32768 + (size_t)tid * 16);
    GL2LDS(pb + 64 * EK,  SM + 40960 + (size_t)tid * 16);
    const u16* pa1 = gA + KCOL(1);
    GL2LDS(pa1,            SM + 49152 + (size_t)tid * 16);
    GL2LDS(pa1 + 64 * K0,  SM + 49152 + 8192 + (size_t)tid * 16);
    GL2LDS(pa1 + 128 * K0, SM + 49152 + 16384 + (size_t)tid * 16);
    GL2LDS(pa1 + 192 * K0, SM + 49152 + 24576 + (size_t)tid * 16);
    const u16* pb1 = gB + KOFFB(1);
    GL2LDS(pb1,            SM + 49152 + 32768 + (size_t)tid * 16);
    GL2LDS(pb1 + 64 * EK,  SM + 49152 + 40960 + (size_t)tid * 16);
  }
  VMW6;    // tile-0's 6 loads landed (6 of tile-1 still in flight)
  LGKM0;   // bls writes visible
  SBAR;

// One K-tile, 2 phases; stages tile T+2 into TGT (3 GL2LDS per phase).
#define TILE(T, CUR, TGT)                                                       \
  {                                                                             \
    const int tn2 = (T) + 2;                                                    \
    /* ---- phase 1: kc0 ---- */                                                \
    {                                                                           \
      bf16x8 af[4], bfv[4];                                                     \
      _Pragma("unroll")                                                         \
      for (int i = 0; i < 4; ++i)                                               \
        af[i] = *(const bf16x8*)(SM + (CUR) + aoff[0][i]);                      \
      _Pragma("unroll")                                                         \
      for (int j = 0; j < 4; ++j)                                               \
        bfv[j] = *(const bf16x8*)(SM + (CUR) + 32768 + boff[0][j]);             \
      if (tn2 < NT) {                                                           \
        const u16* pa = gA + KCOL(tn2);                                         \
        GL2LDS(pa,           SM + (TGT) + (size_t)tid * 16);                    \
        GL2LDS(pa + 64 * K0, SM + (TGT) + 8192 + (size_t)tid * 16);             \
        const u16* pb = gB + KOFFB(tn2);                                        \
        GL2LDS(pb,           SM + (TGT) + 32768 + (size_t)tid * 16);            \
      }                                                                         \
      SBAR;                                                                     \
      LGKM0;                                                                    \
      __builtin_amdgcn_s_setprio(1);                                            \
      _Pragma("unroll")                                                         \
      for (int i = 0; i < 4; ++i)                                               \
        _Pragma("unroll")                                                       \
        for (int j = 0; j < 4; ++j)                                             \
          acc2[i][j] = __builtin_amdgcn_mfma_f32_16x16x32_bf16(af[i], bfv[j],   \
                                                           acc2[i][j], 0, 0, 0);\
      __builtin_amdgcn_s_setprio(0);                                            \
      SBAR;                                                                     \
    }                                                                           \
    /* ---- phase 2: kc1 ---- */                                                \
    {                                                                           \
      bf16x8 af[4], bfv[4];                                                     \
      _Pragma("unroll")                                                         \
      for (int i = 0; i < 4; ++i)                                               \
        af[i] = *(const bf16x8*)(SM + (CUR) + aoff[1][i]);                      \
      _Pragma("unroll")                                                         \
      for (int j = 0; j < 4; ++j)                                               \
        bfv[j] = *(const bf16x8*)(SM + (CUR) + 32768 + boff[1][j]);             \
      if (tn2 < NT) {                                                           \
        const u16* pa = gA + KCOL(tn2);                                         \
        GL2LDS(pa + 128 * K0, SM + (TGT) + 16384 + (size_t)tid * 16);           \
        GL2LDS(pa + 192 * K0, SM + (TGT) + 24576 + (size_t)tid * 16);           \
        const u16* pb = gB + KOFFB(tn2);                                        \
        GL2LDS(pb + 64 * EK,  SM + (TGT) + 40960 + (size_t)tid * 16);           \
      }                                                                         \
      SBAR;                                                                     \
      LGKM0;                                                                    \
      __builtin_amdgcn_s_setprio(1);                                            \
      _Pragma("unroll")                                                         \
      for (int i = 0; i < 4; ++i)                                               \
        _Pragma("unroll")                                                       \
        for (int j = 0; j < 4; ++j)                                             \
          acc2[i][j] = __builtin_amdgcn_mfma_f32_16x16x32_bf16(af[i], bfv[j],   \
                                                           acc2[i][j], 0, 0, 0);\
      __builtin_amdgcn_s_setprio(0);                                            \
    }                                                                           \
    /* expert-boundary fold in the vmcnt shadow */                              \
    if ((((T) + 1) & (TPE - 1)) == 0) {                                         \
      const int e_ = e0 + ((T) >> LTPE);                                        \
      _Pragma("unroll")                                                         \
      for (int mt = 0; mt < 4; ++mt) {                                          \
        float bl[4];                                                            \
        _Pragma("unroll")                                                       \
        for (int r = 0; r < 4; ++r)                                             \
          bl[r] = bls[(wm * 64 + mt * 16 + quad * 4 + r) * 9 + e_];             \
        _Pragma("unroll")                                                       \
        for (int nt = 0; nt < 4; ++nt)                                          \
          _Pragma("unroll")                                                     \
          for (int r = 0; r < 4; ++r) {                                         \
            acc[mt][nt][r] += bl[r] * acc2[mt][nt][r];                          \
            acc2[mt][nt][r] = 0.f;                                              \
          }                                                                     \
      }                                                                         \
    }                                                                           \
    if (tn2 < NT) { VMW6; } else { VMW0; }                                      \
    SBAR;                                                                       \
  }

  uint32_t c0 = 0, c1 = 49152, c2 = 98304;
  #pragma unroll 1
  for (int t = 0; t < NT; t += 2) {
    TILE(t,     c0, c2);
    TILE(t + 1, c1, c0);
    const uint32_t tmp = c2; c2 = c1; c1 = c0; c0 = tmp;
  }
#undef TILE
#undef KOFFB
#undef KCOL

  // Coalesced epilogue via per-wave LDS transpose (SM free after final barrier;
  // each wave uses a private 4 KB segment). C/D: col=lane&15, row=quad*4+reg.
  u16* Ps = P + (size_t)blockIdx.z * ((size_t)BATCH * N);
  u16* ls = (u16*)SM + w * 2048;   // 32 rows x 64 cols u16 per wave
  #pragma unroll
  for (int half = 0; half < 2; ++half) {
    #pragma unroll
    for (int mh = 0; mh < 2; ++mh) {
      int mt = half * 2 + mh;
      #pragma unroll
      for (int r = 0; r < 4; ++r) {
        int rloc = mh * 16 + quad * 4 + r;          // 0..31
        #pragma unroll
        for (int nt = 0; nt < 4; ++nt) {
          int col = nt * 16 + lrow;                 // 0..63
          int c8 = (col >> 3) ^ (rloc & 7);         // XOR-8 chunk swizzle
          ls[rloc * 64 + (c8 << 3) + (col & 7)] = f2bf(acc[mt][nt][r]);
        }
      }
    }
    #pragma unroll
    for (int p = 0; p < 4; ++p) {
      int rloc = p * 8 + (lane >> 3);               // 0..31
      int c8 = (lane & 7) ^ (rloc & 7);
      u16x8 v = *(const u16x8*)&ls[rloc * 64 + (c8 << 3)];
      int row = row0 + wm * 64 + half * 32 + rloc;
      int colg = col0 + wn * 64 + ((lane & 7) << 3);
      *(u16x8*)&Ps[(size_t)row * N + colg] = v;
    }
  }
}

extern "C" void kernel_launch(void* const* d_in, const int* in_sizes, int n_in,
                              void* d_out, int out_size, void* d_ws, size_t ws_size,
                              hipStream_t stream) {
  const float* blend = (const float*)d_in[0];
  const float* x  = (const float*)d_in[1];
  const float* W0 = (const float*)d_in[2];
  const float* B0 = (const float*)d_in[3];
  const float* W1 = (const float*)d_in[4];
  const float* B1 = (const float*)d_in[5];
  const float* W2 = (const float*)d_in[6];
  const float* B2 = (const float*)d_in[7];
  float* out = (float*)d_out;

  char* ws = (char*)d_ws;
  u16* hA  = (u16*)ws;                           // h0 (4096x512) then h2 (4096x1024); 8.4 MB
  u16* h1  = (u16*)(ws + 8388608);               // 4096x1024 bf16, 8.4 MB
  u16* Bt0 = (u16*)(ws + 16777216);              // 1024 x 4096 bf16, 8.4 MB
  u16* Bt1 = (u16*)(ws + 25165824);              // 1024 x 8192 bf16, 16.8 MB
  u16* Bt2 = (u16*)(ws + 41943040);              // 512 x 8192 bf16, 8.4 MB
  u16* P   = (u16*)(ws + 50331648);              // bf16 partials (unchanged)

  // prep: cast x -> h0 and convert all three W to bf16 Bt layout (one dispatch)
  prep_kernel<<<9216, 256, 0, stream>>>(x, W0, W1, W2, hA, Bt0, Bt1, Bt2);

  // Layer 0: K0=512, 2 slices x 4 experts; bias+ELU in combine
  gemm_fold8_kernel<512, 4><<<dim3(16, 8, 2), 512, 0, stream>>>(hA, Bt0, blend, P, 1024);
  combineS_kernel<2, true, true><<<2048, 256, 0, stream>>>(P, blend, B0, h1, 1024);

  // Layer 1: K0=1024, 2 slices x 4 experts
  gemm_fold8_kernel<1024, 4><<<dim3(16, 8, 2), 512, 0, stream>>>(h1, Bt1, blend, P, 1024);
  combineS_kernel<2, true, true><<<2048, 256, 0, stream>>>(P, blend, B1, hA, 1024);

  // Layer 2: K0=1024, N=512, 4 slices x 2 experts; linear, fp32 out
  gemm_fold8_kernel<1024, 2><<<dim3(16, 4, 4), 512, 0, stream>>>(hA, Bt2, blend, P, 512);
  combineS_kernel<4, false, false><<<1024, 256, 0, stream>>>(P, blend, B2, out, 512);
}